// Round 1
// 266.521 us; speedup vs baseline: 1.0007x; 1.0007x over previous
//
#include <hip/hip_runtime.h>

// B-spline basis, DF=16, DEGREE=3, fixed knots:
// KNOTS = [0,0,0] ++ linspace(0, 1+1e-7, 14) ++ [1,1,1]   (20 knots)
// Output shape (32, 131072, 16) float32.
// Memory-bound: 268 MB out + 17 MB in => ~45 us floor at 6.4 TB/s.
//
// R1: per-thread row stores -> 64 partial sector writes/instr -> ~3 TB/s.
// R2: quad-shuffle transpose -> 256B-strided wave footprint. Worst round.
// R3: LDS transpose + output-linear drain (1KB contiguous per wave-instr,
//     fillBuffer pattern) -> kernel ~57us, ~5 TB/s. WIN.
// R4: nontemporal loads/stores via native ext_vector_type(4).
// R5 (this round): replace the dense Cox-de Boor triangle (~420 VALU
//     ops/elem; compiler can't fold the structural zeros) with the
//     local-support de Boor evaluation: exactly 4 basis functions are
//     nonzero at any t. Interval d = clamp((int)(t*13/(1+1e-7)), 0, 12);
//     knots are clamped-linear: knot[i] = clamp(STEP*(i-3), 0, 1).
//     ~80 VALU ops/elem, rcpf for the 6 divisions (err ~1e-7, absmax
//     headroom is 2^-8). Row written as 4x zero b128 + 4x scattered b32
//     (per-lane LDS addressing; same-wave DS ordering via lgkmcnt).
//     Drain phase unchanged. Prediction: kernel ~47us, VALUBusy /3.

typedef float vfloat4 __attribute__((ext_vector_type(4)));

// Row stride 5 vfloat4 (4 data + 1 pad) = 20 floats: lane l's row starts at
// bank (20*l)%32, uniform spread over banks in both LDS phases. 64 rows x
// 80B = 5 KB/wave, 20 KB/block -> 8 blocks/CU (full occupancy).
#define ROW_STRIDE 5

__global__ __launch_bounds__(256) void bspline_basis_kernel(
    const float* __restrict__ ts, float* __restrict__ out, int n)
{
    // Interior knots are uniform with spacing STEP; the triple knots at the
    // ends are reproduced by clamping the linear formula.
    constexpr float STEP     = (float)((1.0 + 1e-07) / 13.0);
    constexpr float INV_STEP = (float)(13.0 / (1.0 + 1e-07));

    __shared__ vfloat4 lds[4][64 * ROW_STRIDE];

    const int tid  = threadIdx.x;
    const int wave = tid >> 6;
    const int lane = tid & 63;
    const int gid  = blockIdx.x * 256 + tid;

    // ---- Phase 1: one element per thread, local-support de Boor ----
    {
        int e = gid < n ? gid : (n - 1);
        float t = __builtin_nontemporal_load(ts + e);

        // Knot interval: t in [knot[d+3], knot[d+4]), d in [0,12].
        // Boundary misclassification (~1 ulp of t) is covered by C2
        // continuity of the basis -> value error ~1e-6, well in tolerance.
        int d = (int)(t * INV_STEP);
        d = d < 0 ? 0 : (d > 12 ? 12 : d);
        float df = (float)d;

        // knot[d+3+o] = clamp(STEP*(d+o), 0, 1). k0/kp1 need no clamp
        // (0 <= STEP*d < 1; STEP*(d+1) <= 13*STEP ~= knot[16]).
        float km2 = fmaxf(STEP * (df - 2.0f), 0.0f);   // knot[j-2]
        float km1 = fmaxf(STEP * (df - 1.0f), 0.0f);   // knot[j-1]
        float k0  = STEP * df;                          // knot[j]
        float kp1 = STEP * (df + 1.0f);                 // knot[j+1]
        float kp2 = fminf(STEP * (df + 2.0f), 1.0f);   // knot[j+2]
        float kp3 = fminf(STEP * (df + 3.0f), 1.0f);   // knot[j+3]

        float l1 = t - k0, l2 = t - km1, l3 = t - km2;
        float r1 = kp1 - t, r2 = kp2 - t, r3 = kp3 - t;

        // de Boor local recursion: N[r] over degrees 1..3. All spans that
        // appear as denominators contain interval j, hence are nonzero.
        float N0, N1, N2, N3;
        {   // p = 1
            float t0 = __builtin_amdgcn_rcpf(r1 + l1);
            N0 = r1 * t0;
            N1 = l1 * t0;
        }
        {   // p = 2
            float t0 = N0 * __builtin_amdgcn_rcpf(r1 + l2);
            N0 = r1 * t0;
            float sv = l2 * t0;
            float t1 = N1 * __builtin_amdgcn_rcpf(r2 + l1);
            N1 = sv + r2 * t1;
            N2 = l1 * t1;
        }
        {   // p = 3
            float t0 = N0 * __builtin_amdgcn_rcpf(r1 + l3);
            N0 = r1 * t0;
            float sv = l3 * t0;
            float t1 = N1 * __builtin_amdgcn_rcpf(r2 + l2);
            N1 = sv + r2 * t1;
            sv = l2 * t1;
            float t2 = N2 * __builtin_amdgcn_rcpf(r3 + l1);
            N2 = sv + r3 * t2;
            N3 = l1 * t2;
        }

        // Row = 12 zeros + N0..N3 at positions d..d+3 (d+3 <= 15).
        vfloat4* rowv = &lds[wave][lane * ROW_STRIDE];
        rowv[0] = (vfloat4){0.0f, 0.0f, 0.0f, 0.0f};
        rowv[1] = (vfloat4){0.0f, 0.0f, 0.0f, 0.0f};
        rowv[2] = (vfloat4){0.0f, 0.0f, 0.0f, 0.0f};
        rowv[3] = (vfloat4){0.0f, 0.0f, 0.0f, 0.0f};
        float* rowf = reinterpret_cast<float*>(rowv);
        rowf[d]     = N0;
        rowf[d + 1] = N1;
        rowf[d + 2] = N2;
        rowf[d + 3] = N3;
    }

    // No __syncthreads: each wave reads back only its own LDS region; the
    // ds_write -> ds_read dependency within a wave is ordered by the
    // compiler-inserted s_waitcnt lgkmcnt.

    // ---- Phase 2: drain this wave's 64 elements in output-linear order ----
    // Each of the 4 store instructions is one contiguous, aligned 1 KB wave
    // span (fillBuffer pattern), nontemporal (write-once, don't dirty L2).
    const size_t wbase4 = ((size_t)blockIdx.x * 256 + wave * 64) * 4;
    const size_t limit4 = (size_t)n * 4;
    vfloat4* o = reinterpret_cast<vfloat4*>(out) + wbase4;
#pragma unroll
    for (int m = 0; m < 4; ++m) {
        int idx = lane + 64 * m;          // wave-local vfloat4 index
        int e = idx >> 2;                 // source row in this wave's region
        int l = idx & 3;                  // quarter of the row
        vfloat4 v = lds[wave][e * ROW_STRIDE + l];
        if (wbase4 + (size_t)idx < limit4) {
            __builtin_nontemporal_store(v, o + idx);
        }
    }
}

extern "C" void kernel_launch(void* const* d_in, const int* in_sizes, int n_in,
                              void* d_out, int out_size, void* d_ws, size_t ws_size,
                              hipStream_t stream) {
    const float* ts = (const float*)d_in[0];
    float* out = (float*)d_out;
    int n = in_sizes[0];  // 32 * 131072 = 4194304

    const int block = 256;
    const int grid = (n + block - 1) / block;
    bspline_basis_kernel<<<grid, block, 0, stream>>>(ts, out, n);
}